// Round 18
// baseline (244.087 us; speedup 1.0000x reference)
//
#include <hip/hip_runtime.h>
#include <math.h>

#define N_NODES 50000
#define N_EDGESC 2000
#define N_INC   200000
#define SEQ     64
#define FEATN   6
#define CH      32
#define OUTF    5
#define SLOPE   0.01f
#define NSB     196   // ceil(50000/256) node-scan blocks

typedef __attribute__((ext_vector_type(8))) short bf16x8;
typedef __attribute__((ext_vector_type(4))) float f32x4;
typedef __attribute__((ext_vector_type(16))) float f32x16;

__device__ __forceinline__ float fast_rcp(float x) { return __builtin_amdgcn_rcpf(x); }
__device__ __forceinline__ float sigm(float x) { return fast_rcp(1.f + __expf(-x)); }
__device__ __forceinline__ float tanh_fast(float x) { return 1.f - 2.f * fast_rcp(1.f + __expf(2.f * x)); }
__device__ __forceinline__ float leaky(float v) { return v > 0.f ? v : SLOPE * v; }

__device__ __forceinline__ ushort f2bf(float x) {
  uint u = __float_as_uint(x);
  u = u + 0x7fffu + ((u >> 16) & 1u);
  return (ushort)(u >> 16);
}
__device__ __forceinline__ float bf2f(ushort s) {
  return __uint_as_float(((uint)s) << 16);
}
__device__ __forceinline__ uint pk_bf16(float a, float b) {
  uint r;
  asm("v_cvt_pk_bf16_f32 %0, %1, %2" : "=v"(r) : "v"(a), "v"(b));
  return r;
}

union BW { bf16x8 v; uint w[4]; };

// ---------------- GRU via 32x32x16 MFMA: one wave = 32 nodes, H in-register ----------------
// Round-18: __launch_bounds__(64, 1).  r17 analysis: VALU issue/wave-step
// ~1140 vs ~300 in source at VGPR_Count=128 -- live state at the MFMA
// cluster (~64 acc + 48 frags + 16 hst + temps) exceeds the 128 cap, so the
// allocator spills/remats inside the t-loop.  Occupancy is grid-limited at
// 1.53 waves/SIMD (13.4%), so the cap buys nothing; min-waves=1 lets the
// allocator use up to 512 VGPRs.  unroll-2 dropped (null in r16, doubles
// live ranges).  Math bit-identical to r14/r16 (6.1e-5 known good).
__global__ __launch_bounds__(64, 1) void gru_mfma_kernel(
    const float* __restrict__ price,
    const float* __restrict__ w_ih, const float* __restrict__ w_hh,
    const float* __restrict__ b_ih, const float* __restrict__ b_hh,
    float* __restrict__ Y)
{
  __shared__ __align__(16) float Hfin[32 * 36];

  const int lane = threadIdx.x & 63;
  const int c = lane & 31;
  const int s = lane >> 5;
  const int node = blockIdx.x * 32 + c;
  const int nodeC = node < N_NODES ? node : N_NODES - 1;

  bf16x8 WA1hi[3], WA1lo[3], WA2hi[3], WA2lo[3];
#pragma unroll
  for (int T = 0; T < 3; ++T) {
    const float* wr = w_hh + (T * 32 + c) * CH;
    {
      const float* p = wr + 8 * s;
      float4 v0 = *(const float4*)(p);
      float4 v1 = *(const float4*)(p + 4);
      float vv[8] = {v0.x, v0.y, v0.z, v0.w, v1.x, v1.y, v1.z, v1.w};
#pragma unroll
      for (int e = 0; e < 8; ++e) {
        ushort h = f2bf(vv[e]);
        WA1hi[T][e] = (short)h;
        WA1lo[T][e] = (short)f2bf(vv[e] - bf2f(h));
      }
    }
    {
      const float* p = wr + 16 + 8 * s;
      float4 v0 = *(const float4*)(p);
      float4 v1 = *(const float4*)(p + 4);
      float vv[8] = {v0.x, v0.y, v0.z, v0.w, v1.x, v1.y, v1.z, v1.w};
#pragma unroll
      for (int e = 0; e < 8; ++e) {
        ushort h = f2bf(vv[e]);
        WA2hi[T][e] = (short)h;
        WA2lo[T][e] = (short)f2bf(vv[e] - bf2f(h));
      }
    }
  }

  bf16x8 GA1[3], GA2[3];
#pragma unroll
  for (int T = 0; T < 3; ++T) {
    int g = T * 32 + c;
    float w[6]; ushort wh[6]; float wl[6];
#pragma unroll
    for (int f = 0; f < FEATN; ++f) w[f] = w_ih[g * FEATN + f];
#pragma unroll
    for (int f = 0; f < FEATN; ++f) { wh[f] = f2bf(w[f]); wl[f] = w[f] - bf2f(wh[f]); }
    bf16x8 a1 = {0, 0, 0, 0, 0, 0, 0, 0};
    bf16x8 a2 = {0, 0, 0, 0, 0, 0, 0, 0};
    if (s == 0) {
#pragma unroll
      for (int f = 0; f < 6; ++f) a1[f] = (short)wh[f];
      a1[6] = (short)wh[0]; a1[7] = (short)wh[1];
#pragma unroll
      for (int f = 0; f < 6; ++f) a2[f] = (short)f2bf(wl[f]);
    } else {
      a1[0] = (short)wh[2]; a1[1] = (short)wh[3];
      a1[2] = (short)wh[4]; a1[3] = (short)wh[5];
      float bias = b_ih[g] + (g < 64 ? b_hh[g] : 0.f);
      ushort bh = f2bf(bias);
      a1[4] = (short)bh;
      a1[5] = (short)f2bf(bias - bf2f(bh));
    }
    GA1[T] = a1; GA2[T] = a2;
  }

  f32x16 bhnC, zz16;
#pragma unroll
  for (int i = 0; i < 16; ++i) {
    int u = (i & 3) + 8 * (i >> 2) + 4 * s;
    bhnC[i] = b_hh[64 + u];
    zz16[i] = 0.f;
  }

  float hst[16];
#pragma unroll
  for (int i = 0; i < 16; ++i) hst[i] = 0.f;

  const float* xp = price + nodeC * (SEQ * FEATN);

  float xc0, xc1, xc2, xc3, xc4, xc5;
  {
    float2 a0 = *(const float2*)(xp);
    float2 a1 = *(const float2*)(xp + 2);
    float2 a2 = *(const float2*)(xp + 4);
    xc0 = a0.x; xc1 = a0.y; xc2 = a1.x; xc3 = a1.y; xc4 = a2.x; xc5 = a2.y;
  }

  for (int t = 0; t < SEQ; ++t) {
    uint p01 = pk_bf16(xc0, xc1);
    uint p23 = pk_bf16(xc2, xc3);
    uint p45 = pk_bf16(xc4, xc5);
    float l0 = xc0 - __uint_as_float(p01 << 16);
    float l1 = xc1 - __uint_as_float(p01 & 0xFFFF0000u);
    float l2 = xc2 - __uint_as_float(p23 << 16);
    float l3 = xc3 - __uint_as_float(p23 & 0xFFFF0000u);
    float l4 = xc4 - __uint_as_float(p45 << 16);
    float l5 = xc5 - __uint_as_float(p45 & 0xFFFF0000u);
    uint lo01 = pk_bf16(l0, l1);
    uint lo23 = pk_bf16(l2, l3);
    uint lo45 = pk_bf16(l4, l5);
    BW bx1, bx2;
    if (s == 0) {
      bx1.w[0] = p01; bx1.w[1] = p23; bx1.w[2] = p45; bx1.w[3] = lo01;
      bx2.w[0] = p01; bx2.w[1] = p23; bx2.w[2] = p45; bx2.w[3] = 0;
    } else {
      bx1.w[0] = lo23; bx1.w[1] = lo45; bx1.w[2] = 0x3F803F80u; bx1.w[3] = 0;
      bx2.w[0] = 0; bx2.w[1] = 0; bx2.w[2] = 0; bx2.w[3] = 0;
    }

    if (t + 1 < SEQ) {
      const float* nx = xp + (t + 1) * FEATN;
      float2 a0 = *(const float2*)(nx);
      float2 a1 = *(const float2*)(nx + 2);
      float2 a2 = *(const float2*)(nx + 4);
      xc0 = a0.x; xc1 = a0.y; xc2 = a1.x; xc3 = a1.y; xc4 = a2.x; xc5 = a2.y;
    }

    uint Dh[8], Dl[8];
#pragma unroll
    for (int k = 0; k < 8; ++k) {
      uint ph = pk_bf16(hst[2 * k], hst[2 * k + 1]);
      Dh[k] = ph;
      float e0 = hst[2 * k]     - __uint_as_float(ph << 16);
      float e1 = hst[2 * k + 1] - __uint_as_float(ph & 0xFFFF0000u);
      Dl[k] = pk_bf16(e0, e1);
    }
    uint u0h = (uint)__shfl_xor((int)(s ? Dh[0] : Dh[2]), 32);
    uint u1h = (uint)__shfl_xor((int)(s ? Dh[1] : Dh[3]), 32);
    uint u2h = (uint)__shfl_xor((int)(s ? Dh[4] : Dh[6]), 32);
    uint u3h = (uint)__shfl_xor((int)(s ? Dh[5] : Dh[7]), 32);
    uint u0l = (uint)__shfl_xor((int)(s ? Dl[0] : Dl[2]), 32);
    uint u1l = (uint)__shfl_xor((int)(s ? Dl[1] : Dl[3]), 32);
    uint u2l = (uint)__shfl_xor((int)(s ? Dl[4] : Dl[6]), 32);
    uint u3l = (uint)__shfl_xor((int)(s ? Dl[5] : Dl[7]), 32);
    BW b1h, b2h, b1l, b2l;
    b1h.w[0] = s ? u0h : Dh[0]; b1h.w[1] = s ? u1h : Dh[1];
    b1h.w[2] = s ? Dh[2] : u0h; b1h.w[3] = s ? Dh[3] : u1h;
    b2h.w[0] = s ? u2h : Dh[4]; b2h.w[1] = s ? u3h : Dh[5];
    b2h.w[2] = s ? Dh[6] : u2h; b2h.w[3] = s ? Dh[7] : u3h;
    b1l.w[0] = s ? u0l : Dl[0]; b1l.w[1] = s ? u1l : Dl[1];
    b1l.w[2] = s ? Dl[2] : u0l; b1l.w[3] = s ? Dl[3] : u1l;
    b2l.w[0] = s ? u2l : Dl[4]; b2l.w[1] = s ? u3l : Dl[5];
    b2l.w[2] = s ? Dl[6] : u2l; b2l.w[3] = s ? Dl[7] : u3l;

    f32x16 aR = __builtin_amdgcn_mfma_f32_32x32x16_bf16(GA1[0], bx1.v, zz16, 0, 0, 0);
    aR = __builtin_amdgcn_mfma_f32_32x32x16_bf16(GA2[0], bx2.v, aR, 0, 0, 0);
    aR = __builtin_amdgcn_mfma_f32_32x32x16_bf16(WA1lo[0], b1h.v, aR, 0, 0, 0);
    aR = __builtin_amdgcn_mfma_f32_32x32x16_bf16(WA2lo[0], b2h.v, aR, 0, 0, 0);
    aR = __builtin_amdgcn_mfma_f32_32x32x16_bf16(WA1hi[0], b1l.v, aR, 0, 0, 0);
    aR = __builtin_amdgcn_mfma_f32_32x32x16_bf16(WA2hi[0], b2l.v, aR, 0, 0, 0);
    aR = __builtin_amdgcn_mfma_f32_32x32x16_bf16(WA1hi[0], b1h.v, aR, 0, 0, 0);
    aR = __builtin_amdgcn_mfma_f32_32x32x16_bf16(WA2hi[0], b2h.v, aR, 0, 0, 0);

    f32x16 aZ = __builtin_amdgcn_mfma_f32_32x32x16_bf16(GA1[1], bx1.v, zz16, 0, 0, 0);
    aZ = __builtin_amdgcn_mfma_f32_32x32x16_bf16(GA2[1], bx2.v, aZ, 0, 0, 0);
    aZ = __builtin_amdgcn_mfma_f32_32x32x16_bf16(WA1lo[1], b1h.v, aZ, 0, 0, 0);
    aZ = __builtin_amdgcn_mfma_f32_32x32x16_bf16(WA2lo[1], b2h.v, aZ, 0, 0, 0);
    aZ = __builtin_amdgcn_mfma_f32_32x32x16_bf16(WA1hi[1], b1l.v, aZ, 0, 0, 0);
    aZ = __builtin_amdgcn_mfma_f32_32x32x16_bf16(WA2hi[1], b2l.v, aZ, 0, 0, 0);
    aZ = __builtin_amdgcn_mfma_f32_32x32x16_bf16(WA1hi[1], b1h.v, aZ, 0, 0, 0);
    aZ = __builtin_amdgcn_mfma_f32_32x32x16_bf16(WA2hi[1], b2h.v, aZ, 0, 0, 0);

    f32x16 aNi = __builtin_amdgcn_mfma_f32_32x32x16_bf16(GA1[2], bx1.v, zz16, 0, 0, 0);
    aNi = __builtin_amdgcn_mfma_f32_32x32x16_bf16(GA2[2], bx2.v, aNi, 0, 0, 0);
    f32x16 aNh = __builtin_amdgcn_mfma_f32_32x32x16_bf16(WA1lo[2], b1h.v, bhnC, 0, 0, 0);
    aNh = __builtin_amdgcn_mfma_f32_32x32x16_bf16(WA2lo[2], b2h.v, aNh, 0, 0, 0);
    aNh = __builtin_amdgcn_mfma_f32_32x32x16_bf16(WA1hi[2], b1l.v, aNh, 0, 0, 0);
    aNh = __builtin_amdgcn_mfma_f32_32x32x16_bf16(WA2hi[2], b2l.v, aNh, 0, 0, 0);
    aNh = __builtin_amdgcn_mfma_f32_32x32x16_bf16(WA1hi[2], b1h.v, aNh, 0, 0, 0);
    aNh = __builtin_amdgcn_mfma_f32_32x32x16_bf16(WA2hi[2], b2h.v, aNh, 0, 0, 0);

#pragma unroll
    for (int i = 0; i < 16; ++i) {
      float r = sigm(aR[i]);
      float z = sigm(aZ[i]);
      float n = tanh_fast(aNi[i] + r * aNh[i]);
      hst[i] = n + z * (hst[i] - n);
    }
  }

#pragma unroll
  for (int k = 0; k < 8; ++k) {
    int u = ((2 * k) & 3) + 8 * ((2 * k) >> 2) + 4 * s;
    *(float2*)(&Hfin[c * 36 + u]) = make_float2(hst[2 * k], hst[2 * k + 1]);
  }
  __syncthreads();
  {
    int mm = lane >> 1, half = lane & 1;
    int onode = blockIdx.x * 32 + mm;
    if (onode < N_NODES) {
      const float* src = &Hfin[mm * 36 + half * 16];
      float4 v0 = *(const float4*)(src);
      float4 v1 = *(const float4*)(src + 4);
      float4 v2 = *(const float4*)(src + 8);
      float4 v3 = *(const float4*)(src + 12);
      float* dst = Y + onode * CH + half * 16;
      *(float4*)(dst) = v0; *(float4*)(dst + 4) = v1;
      *(float4*)(dst + 8) = v2; *(float4*)(dst + 12) = v3;
    }
  }
}

// ---------------- node degree counting ----------------
__global__ __launch_bounds__(256) void deg_kernel(
    const int* __restrict__ nodes, int* __restrict__ DN)
{
  int i = blockIdx.x * 256 + threadIdx.x;
  if (i < N_INC) atomicAdd(&DN[nodes[i]], 1);
}

// ---------------- parallel node-degree scan: phase 1 (block sums) ----------------
__global__ __launch_bounds__(256) void nsum_kernel(
    const int* __restrict__ DN, int* __restrict__ Bsum)
{
  int t = threadIdx.x, i = blockIdx.x * 256 + t;
  int v = (i < N_NODES) ? DN[i] : 0;
#pragma unroll
  for (int off = 1; off < 64; off <<= 1) v += __shfl_xor(v, off);
  __shared__ int red[4];
  if ((t & 63) == 0) red[t >> 6] = v;
  __syncthreads();
  if (t == 0) Bsum[blockIdx.x] = red[0] + red[1] + red[2] + red[3];
}

// ---------------- phase 2: scan of NSB block sums (1 block) ----------------
__global__ __launch_bounds__(256) void bscan_kernel(
    const int* __restrict__ Bsum, int* __restrict__ Boff, int* __restrict__ NOFF)
{
  __shared__ int part[256];
  int t = threadIdx.x;
  int x = (t < NSB) ? Bsum[t] : 0;
  part[t] = x;
  __syncthreads();
  for (int d = 1; d < 256; d <<= 1) {
    int v = (t >= d) ? part[t - d] : 0;
    __syncthreads();
    part[t] += v;
    __syncthreads();
  }
  if (t < NSB) Boff[t] = part[t] - x;
  if (t == NSB - 1) NOFF[N_NODES] = part[t];
}

// ---------------- phase 3: per-block local scan + offset -> NOFF, CUR ----------------
__global__ __launch_bounds__(256) void napply_kernel(
    const int* __restrict__ DN, const int* __restrict__ Boff,
    int* __restrict__ NOFF, int* __restrict__ CUR)
{
  __shared__ int part[256];
  int t = threadIdx.x, i = blockIdx.x * 256 + t;
  int x = (i < N_NODES) ? DN[i] : 0;
  part[t] = x;
  __syncthreads();
  for (int d = 1; d < 256; d <<= 1) {
    int v = (t >= d) ? part[t - d] : 0;
    __syncthreads();
    part[t] += v;
    __syncthreads();
  }
  if (i < N_NODES) {
    int excl = part[t] - x + Boff[blockIdx.x];
    NOFF[i] = excl;
    CUR[i] = excl;
  }
}

// ---------------- bucket incidences by node: INCN[pos] = edge ----------------
__global__ __launch_bounds__(256) void bucket_kernel(
    const int* __restrict__ nodes, const int* __restrict__ edges,
    int* __restrict__ CUR, int* __restrict__ INCN)
{
  int i = blockIdx.x * 256 + threadIdx.x;
  if (i < N_INC) {
    int p = atomicAdd(&CUR[nodes[i]], 1);
    INCN[p] = edges[i];
  }
}

// ---------------- node->edge gather-sum + fused theta (range via binary search) ----------------
__global__ __launch_bounds__(256) void edge_gather_kernel(
    const float* __restrict__ X, const int* __restrict__ nodes,
    const int* __restrict__ edges, const float* __restrict__ theta,
    float* __restrict__ EF)
{
  int e = blockIdx.x;
  int lo = 0, hi = N_INC;
  while (lo < hi) { int mid = (lo + hi) >> 1; if (edges[mid] < e) lo = mid + 1; else hi = mid; }
  int s = lo;
  hi = N_INC;
  while (lo < hi) { int mid = (lo + hi) >> 1; if (edges[mid] < e + 1) lo = mid + 1; else hi = mid; }
  int tE = lo;

  int f = threadIdx.x & 31, g = threadIdx.x >> 5;
  float a0 = 0.f, a1 = 0.f;
  for (int i = s + g; i < tE; i += 16) {
    a0 += X[nodes[i] * CH + f];
    if (i + 8 < tE) a1 += X[nodes[i + 8] * CH + f];
  }
  __shared__ float red[8][33];
  __shared__ __align__(16) float e32[32];
  red[g][f] = a0 + a1;
  __syncthreads();
  if (threadIdx.x < 32) {
    float acc = 0.f;
#pragma unroll
    for (int r = 0; r < 8; ++r) acc += red[r][f];
    int cnt = tE - s;
    float binv = cnt > 0 ? 1.f / (float)cnt : 0.f;
    e32[f] = acc * binv;
    float s0 = 0.f, s1 = 0.f;
#pragma unroll
    for (int k4 = 0; k4 < 8; ++k4) {
      float4 ev = *(float4*)(e32 + 4 * k4);
      float4 tv = *(const float4*)(theta + f * CH + 4 * k4);
      s0 += tv.x * ev.x + tv.z * ev.z;
      s1 += tv.y * ev.y + tv.w * ev.w;
    }
    EF[e * CH + f] = s0 + s1;
  }
}

// ---------------- edge->node CSR gather + finalize (conv1) ----------------
__global__ __launch_bounds__(256) void node_gather_kernel(
    const float* __restrict__ EF, const int* __restrict__ NOFF,
    const int* __restrict__ INCN, const float* __restrict__ bias,
    float* __restrict__ X)
{
  int gid = blockIdx.x * 256 + threadIdx.x;
  if (gid >= N_NODES * 8) return;
  int n = gid >> 3, q = gid & 7;
  int s = NOFF[n], e = NOFF[n + 1];
  float4 acc = make_float4(0.f, 0.f, 0.f, 0.f);
  float4 acc2 = make_float4(0.f, 0.f, 0.f, 0.f);
  int k = s;
  for (; k + 1 < e; k += 2) {
    int e0 = INCN[k], e1 = INCN[k + 1];
    float4 v0 = *(const float4*)(EF + e0 * CH + q * 4);
    float4 v1 = *(const float4*)(EF + e1 * CH + q * 4);
    acc.x += v0.x; acc.y += v0.y; acc.z += v0.z; acc.w += v0.w;
    acc2.x += v1.x; acc2.y += v1.y; acc2.z += v1.z; acc2.w += v1.w;
  }
  if (k < e) {
    float4 v0 = *(const float4*)(EF + INCN[k] * CH + q * 4);
    acc.x += v0.x; acc.y += v0.y; acc.z += v0.z; acc.w += v0.w;
  }
  int d = e - s;
  float dinv = d > 0 ? 1.f / (float)d : 0.f;
  float4 b = *(const float4*)(bias + 4 * q);
  float4 o;
  o.x = leaky(fmaf(acc.x + acc2.x, dinv, b.x));
  o.y = leaky(fmaf(acc.y + acc2.y, dinv, b.y));
  o.z = leaky(fmaf(acc.z + acc2.z, dinv, b.z));
  o.w = leaky(fmaf(acc.w + acc2.w, dinv, b.w));
  *(float4*)(X + n * CH + 4 * q) = o;
}

// ---------------- edge->node CSR gather + finalize + output linear (conv2) ----------------
__global__ __launch_bounds__(256) void node_gather_out_kernel(
    const float* __restrict__ EF, const int* __restrict__ NOFF,
    const int* __restrict__ INCN, const float* __restrict__ bias,
    const float* __restrict__ w_out, const float* __restrict__ b_out,
    float* __restrict__ out)
{
  int gid = blockIdx.x * 256 + threadIdx.x;
  if (gid >= N_NODES * 8) return;
  int n = gid >> 3, q = gid & 7;
  int s = NOFF[n], e = NOFF[n + 1];
  float4 acc = make_float4(0.f, 0.f, 0.f, 0.f);
  float4 acc2 = make_float4(0.f, 0.f, 0.f, 0.f);
  int k = s;
  for (; k + 1 < e; k += 2) {
    int e0 = INCN[k], e1 = INCN[k + 1];
    float4 v0 = *(const float4*)(EF + e0 * CH + q * 4);
    float4 v1 = *(const float4*)(EF + e1 * CH + q * 4);
    acc.x += v0.x; acc.y += v0.y; acc.z += v0.z; acc.w += v0.w;
    acc2.x += v1.x; acc2.y += v1.y; acc2.z += v1.z; acc2.w += v1.w;
  }
  if (k < e) {
    float4 v0 = *(const float4*)(EF + INCN[k] * CH + q * 4);
    acc.x += v0.x; acc.y += v0.y; acc.z += v0.z; acc.w += v0.w;
  }
  int d = e - s;
  float dinv = d > 0 ? 1.f / (float)d : 0.f;
  float4 b = *(const float4*)(bias + 4 * q);
  float v0 = leaky(fmaf(acc.x + acc2.x, dinv, b.x));
  float v1 = leaky(fmaf(acc.y + acc2.y, dinv, b.y));
  float v2 = leaky(fmaf(acc.z + acc2.z, dinv, b.z));
  float v3 = leaky(fmaf(acc.w + acc2.w, dinv, b.w));

  float p[OUTF];
#pragma unroll
  for (int o = 0; o < OUTF; ++o) {
    const float* wr = w_out + o * CH + 4 * q;
    p[o] = v0 * wr[0] + v1 * wr[1] + v2 * wr[2] + v3 * wr[3];
  }
#pragma unroll
  for (int off = 1; off < 8; off <<= 1) {
#pragma unroll
    for (int o = 0; o < OUTF; ++o) p[o] += __shfl_xor(p[o], off);
  }
  if (q < OUTF) out[n * OUTF + q] = leaky(p[q] + b_out[q]);
}

extern "C" void kernel_launch(void* const* d_in, const int* in_sizes, int n_in,
                              void* d_out, int out_size, void* d_ws, size_t ws_size,
                              hipStream_t stream)
{
  const float* price   = (const float*)d_in[0];
  const int*   e_nodes = (const int*)d_in[1];
  const int*   e_edges = (const int*)d_in[2];
  const float* w_ih    = (const float*)d_in[6];
  const float* w_hh    = (const float*)d_in[7];
  const float* b_ih    = (const float*)d_in[8];
  const float* b_hh    = (const float*)d_in[9];
  const float* theta1  = (const float*)d_in[10];
  const float* bias1   = (const float*)d_in[11];
  const float* theta2  = (const float*)d_in[12];
  const float* bias2   = (const float*)d_in[13];
  const float* w_out   = (const float*)d_in[14];
  const float* b_out   = (const float*)d_in[15];
  float* out = (float*)d_out;

  float* ws   = (float*)d_ws;
  float* Y    = ws;                    // [50000*32]
  float* EF   = ws + 1600000;          // [2000*32]
  int*   DN   = (int*)(ws + 1664000);  // [50000]
  int*   NOFF = DN + N_NODES;          // [50001]
  int*   CUR  = NOFF + N_NODES + 1;    // [50000]
  int*   INCN = CUR + N_NODES;         // [200000]
  int*   Bsum = INCN + N_INC;          // [NSB]
  int*   Boff = Bsum + NSB;            // [NSB]

  hipMemsetAsync(DN, 0, N_NODES * sizeof(int), stream);
  deg_kernel<<<(N_INC + 255) / 256, 256, 0, stream>>>(e_nodes, DN);
  nsum_kernel<<<NSB, 256, 0, stream>>>(DN, Bsum);
  bscan_kernel<<<1, 256, 0, stream>>>(Bsum, Boff, NOFF);
  napply_kernel<<<NSB, 256, 0, stream>>>(DN, Boff, NOFF, CUR);
  bucket_kernel<<<(N_INC + 255) / 256, 256, 0, stream>>>(e_nodes, e_edges, CUR, INCN);

  gru_mfma_kernel<<<(N_NODES + 31) / 32, 64, 0, stream>>>(
      price, w_ih, w_hh, b_ih, b_hh, Y);

  edge_gather_kernel<<<N_EDGESC, 256, 0, stream>>>(Y, e_nodes, e_edges, theta1, EF);
  node_gather_kernel<<<(N_NODES * 8 + 255) / 256, 256, 0, stream>>>(EF, NOFF, INCN, bias1, Y);

  edge_gather_kernel<<<N_EDGESC, 256, 0, stream>>>(Y, e_nodes, e_edges, theta2, EF);
  node_gather_out_kernel<<<(N_NODES * 8 + 255) / 256, 256, 0, stream>>>(
      EF, NOFF, INCN, bias2, w_out, b_out, out);
}

// Round 19
// 240.790 us; speedup vs baseline: 1.0137x; 1.0137x over previous
//
#include <hip/hip_runtime.h>
#include <math.h>

#define N_NODES 50000
#define N_EDGESC 2000
#define N_INC   200000
#define SEQ     64
#define FEATN   6
#define CH      32
#define OUTF    5
#define SLOPE   0.01f
#define NSB     196   // ceil(50000/256) node-scan blocks

typedef __attribute__((ext_vector_type(8))) short bf16x8;
typedef __attribute__((ext_vector_type(4))) float f32x4;
typedef __attribute__((ext_vector_type(16))) float f32x16;

__device__ __forceinline__ float fast_rcp(float x) { return __builtin_amdgcn_rcpf(x); }
__device__ __forceinline__ float sigm(float x) { return fast_rcp(1.f + __expf(-x)); }
__device__ __forceinline__ float tanh_fast(float x) { return 1.f - 2.f * fast_rcp(1.f + __expf(2.f * x)); }
__device__ __forceinline__ float leaky(float v) { return v > 0.f ? v : SLOPE * v; }

__device__ __forceinline__ ushort f2bf(float x) {
  uint u = __float_as_uint(x);
  u = u + 0x7fffu + ((u >> 16) & 1u);
  return (ushort)(u >> 16);
}
__device__ __forceinline__ float bf2f(ushort s) {
  return __uint_as_float(((uint)s) << 16);
}
__device__ __forceinline__ uint pk_bf16(float a, float b) {
  uint r;
  asm("v_cvt_pk_bf16_f32 %0, %1, %2" : "=v"(r) : "v"(a), "v"(b));
  return r;
}

union BW { bf16x8 v; uint w[4]; };

// ---------------- GRU via 32x32x16 MFMA (FROZEN at best-known r17 config) ----------------
// Final analysis (r13-r18): 1563 serial 64-step chains over 1024 SIMDs =
// 1.53 streams/SIMD; per step ~96 trans x8cyc + ~380 VALU x2 + 24 MFMA x8
// ~ 1750 issue-cyc/wave-step.  ILP (r13), gate-split occupancy (r15),
// x-staging (r12/r16), register caps (r18) all null/negative: stream count
// is conserved under tiling, so wall = latency-laced issue at 1.53 streams.
__global__ __launch_bounds__(64) void gru_mfma_kernel(
    const float* __restrict__ price,
    const float* __restrict__ w_ih, const float* __restrict__ w_hh,
    const float* __restrict__ b_ih, const float* __restrict__ b_hh,
    float* __restrict__ Y)
{
  __shared__ __align__(16) float Hfin[32 * 36];

  const int lane = threadIdx.x & 63;
  const int c = lane & 31;
  const int s = lane >> 5;
  const int node = blockIdx.x * 32 + c;
  const int nodeC = node < N_NODES ? node : N_NODES - 1;

  bf16x8 WA1hi[3], WA1lo[3], WA2hi[3], WA2lo[3];
#pragma unroll
  for (int T = 0; T < 3; ++T) {
    const float* wr = w_hh + (T * 32 + c) * CH;
    {
      const float* p = wr + 8 * s;
      float4 v0 = *(const float4*)(p);
      float4 v1 = *(const float4*)(p + 4);
      float vv[8] = {v0.x, v0.y, v0.z, v0.w, v1.x, v1.y, v1.z, v1.w};
#pragma unroll
      for (int e = 0; e < 8; ++e) {
        ushort h = f2bf(vv[e]);
        WA1hi[T][e] = (short)h;
        WA1lo[T][e] = (short)f2bf(vv[e] - bf2f(h));
      }
    }
    {
      const float* p = wr + 16 + 8 * s;
      float4 v0 = *(const float4*)(p);
      float4 v1 = *(const float4*)(p + 4);
      float vv[8] = {v0.x, v0.y, v0.z, v0.w, v1.x, v1.y, v1.z, v1.w};
#pragma unroll
      for (int e = 0; e < 8; ++e) {
        ushort h = f2bf(vv[e]);
        WA2hi[T][e] = (short)h;
        WA2lo[T][e] = (short)f2bf(vv[e] - bf2f(h));
      }
    }
  }

  bf16x8 GA1[3], GA2[3];
#pragma unroll
  for (int T = 0; T < 3; ++T) {
    int g = T * 32 + c;
    float w[6]; ushort wh[6]; float wl[6];
#pragma unroll
    for (int f = 0; f < FEATN; ++f) w[f] = w_ih[g * FEATN + f];
#pragma unroll
    for (int f = 0; f < FEATN; ++f) { wh[f] = f2bf(w[f]); wl[f] = w[f] - bf2f(wh[f]); }
    bf16x8 a1 = {0, 0, 0, 0, 0, 0, 0, 0};
    bf16x8 a2 = {0, 0, 0, 0, 0, 0, 0, 0};
    if (s == 0) {
#pragma unroll
      for (int f = 0; f < 6; ++f) a1[f] = (short)wh[f];
      a1[6] = (short)wh[0]; a1[7] = (short)wh[1];
#pragma unroll
      for (int f = 0; f < 6; ++f) a2[f] = (short)f2bf(wl[f]);
    } else {
      a1[0] = (short)wh[2]; a1[1] = (short)wh[3];
      a1[2] = (short)wh[4]; a1[3] = (short)wh[5];
      float bias = b_ih[g] + (g < 64 ? b_hh[g] : 0.f);
      ushort bh = f2bf(bias);
      a1[4] = (short)bh;
      a1[5] = (short)f2bf(bias - bf2f(bh));
    }
    GA1[T] = a1; GA2[T] = a2;
  }

  f32x16 bhnC, zz16;
#pragma unroll
  for (int i = 0; i < 16; ++i) {
    int u = (i & 3) + 8 * (i >> 2) + 4 * s;
    bhnC[i] = b_hh[64 + u];
    zz16[i] = 0.f;
  }

  float hst[16];
#pragma unroll
  for (int i = 0; i < 16; ++i) hst[i] = 0.f;

  const float* xp = price + nodeC * (SEQ * FEATN);

  float xc0, xc1, xc2, xc3, xc4, xc5;
  {
    float2 a0 = *(const float2*)(xp);
    float2 a1 = *(const float2*)(xp + 2);
    float2 a2 = *(const float2*)(xp + 4);
    xc0 = a0.x; xc1 = a0.y; xc2 = a1.x; xc3 = a1.y; xc4 = a2.x; xc5 = a2.y;
  }

#pragma unroll 2
  for (int t = 0; t < SEQ; ++t) {
    uint p01 = pk_bf16(xc0, xc1);
    uint p23 = pk_bf16(xc2, xc3);
    uint p45 = pk_bf16(xc4, xc5);
    float l0 = xc0 - __uint_as_float(p01 << 16);
    float l1 = xc1 - __uint_as_float(p01 & 0xFFFF0000u);
    float l2 = xc2 - __uint_as_float(p23 << 16);
    float l3 = xc3 - __uint_as_float(p23 & 0xFFFF0000u);
    float l4 = xc4 - __uint_as_float(p45 << 16);
    float l5 = xc5 - __uint_as_float(p45 & 0xFFFF0000u);
    uint lo01 = pk_bf16(l0, l1);
    uint lo23 = pk_bf16(l2, l3);
    uint lo45 = pk_bf16(l4, l5);
    BW bx1, bx2;
    if (s == 0) {
      bx1.w[0] = p01; bx1.w[1] = p23; bx1.w[2] = p45; bx1.w[3] = lo01;
      bx2.w[0] = p01; bx2.w[1] = p23; bx2.w[2] = p45; bx2.w[3] = 0;
    } else {
      bx1.w[0] = lo23; bx1.w[1] = lo45; bx1.w[2] = 0x3F803F80u; bx1.w[3] = 0;
      bx2.w[0] = 0; bx2.w[1] = 0; bx2.w[2] = 0; bx2.w[3] = 0;
    }

    if (t + 1 < SEQ) {
      const float* nx = xp + (t + 1) * FEATN;
      float2 a0 = *(const float2*)(nx);
      float2 a1 = *(const float2*)(nx + 2);
      float2 a2 = *(const float2*)(nx + 4);
      xc0 = a0.x; xc1 = a0.y; xc2 = a1.x; xc3 = a1.y; xc4 = a2.x; xc5 = a2.y;
    }

    uint Dh[8], Dl[8];
#pragma unroll
    for (int k = 0; k < 8; ++k) {
      uint ph = pk_bf16(hst[2 * k], hst[2 * k + 1]);
      Dh[k] = ph;
      float e0 = hst[2 * k]     - __uint_as_float(ph << 16);
      float e1 = hst[2 * k + 1] - __uint_as_float(ph & 0xFFFF0000u);
      Dl[k] = pk_bf16(e0, e1);
    }
    uint u0h = (uint)__shfl_xor((int)(s ? Dh[0] : Dh[2]), 32);
    uint u1h = (uint)__shfl_xor((int)(s ? Dh[1] : Dh[3]), 32);
    uint u2h = (uint)__shfl_xor((int)(s ? Dh[4] : Dh[6]), 32);
    uint u3h = (uint)__shfl_xor((int)(s ? Dh[5] : Dh[7]), 32);
    uint u0l = (uint)__shfl_xor((int)(s ? Dl[0] : Dl[2]), 32);
    uint u1l = (uint)__shfl_xor((int)(s ? Dl[1] : Dl[3]), 32);
    uint u2l = (uint)__shfl_xor((int)(s ? Dl[4] : Dl[6]), 32);
    uint u3l = (uint)__shfl_xor((int)(s ? Dl[5] : Dl[7]), 32);
    BW b1h, b2h, b1l, b2l;
    b1h.w[0] = s ? u0h : Dh[0]; b1h.w[1] = s ? u1h : Dh[1];
    b1h.w[2] = s ? Dh[2] : u0h; b1h.w[3] = s ? Dh[3] : u1h;
    b2h.w[0] = s ? u2h : Dh[4]; b2h.w[1] = s ? u3h : Dh[5];
    b2h.w[2] = s ? Dh[6] : u2h; b2h.w[3] = s ? Dh[7] : u3h;
    b1l.w[0] = s ? u0l : Dl[0]; b1l.w[1] = s ? u1l : Dl[1];
    b1l.w[2] = s ? Dl[2] : u0l; b1l.w[3] = s ? Dl[3] : u1l;
    b2l.w[0] = s ? u2l : Dl[4]; b2l.w[1] = s ? u3l : Dl[5];
    b2l.w[2] = s ? Dl[6] : u2l; b2l.w[3] = s ? Dl[7] : u3l;

    f32x16 aR = __builtin_amdgcn_mfma_f32_32x32x16_bf16(GA1[0], bx1.v, zz16, 0, 0, 0);
    aR = __builtin_amdgcn_mfma_f32_32x32x16_bf16(GA2[0], bx2.v, aR, 0, 0, 0);
    aR = __builtin_amdgcn_mfma_f32_32x32x16_bf16(WA1lo[0], b1h.v, aR, 0, 0, 0);
    aR = __builtin_amdgcn_mfma_f32_32x32x16_bf16(WA2lo[0], b2h.v, aR, 0, 0, 0);
    aR = __builtin_amdgcn_mfma_f32_32x32x16_bf16(WA1hi[0], b1l.v, aR, 0, 0, 0);
    aR = __builtin_amdgcn_mfma_f32_32x32x16_bf16(WA2hi[0], b2l.v, aR, 0, 0, 0);
    aR = __builtin_amdgcn_mfma_f32_32x32x16_bf16(WA1hi[0], b1h.v, aR, 0, 0, 0);
    aR = __builtin_amdgcn_mfma_f32_32x32x16_bf16(WA2hi[0], b2h.v, aR, 0, 0, 0);

    f32x16 aZ = __builtin_amdgcn_mfma_f32_32x32x16_bf16(GA1[1], bx1.v, zz16, 0, 0, 0);
    aZ = __builtin_amdgcn_mfma_f32_32x32x16_bf16(GA2[1], bx2.v, aZ, 0, 0, 0);
    aZ = __builtin_amdgcn_mfma_f32_32x32x16_bf16(WA1lo[1], b1h.v, aZ, 0, 0, 0);
    aZ = __builtin_amdgcn_mfma_f32_32x32x16_bf16(WA2lo[1], b2h.v, aZ, 0, 0, 0);
    aZ = __builtin_amdgcn_mfma_f32_32x32x16_bf16(WA1hi[1], b1l.v, aZ, 0, 0, 0);
    aZ = __builtin_amdgcn_mfma_f32_32x32x16_bf16(WA2hi[1], b2l.v, aZ, 0, 0, 0);
    aZ = __builtin_amdgcn_mfma_f32_32x32x16_bf16(WA1hi[1], b1h.v, aZ, 0, 0, 0);
    aZ = __builtin_amdgcn_mfma_f32_32x32x16_bf16(WA2hi[1], b2h.v, aZ, 0, 0, 0);

    f32x16 aNi = __builtin_amdgcn_mfma_f32_32x32x16_bf16(GA1[2], bx1.v, zz16, 0, 0, 0);
    aNi = __builtin_amdgcn_mfma_f32_32x32x16_bf16(GA2[2], bx2.v, aNi, 0, 0, 0);
    f32x16 aNh = __builtin_amdgcn_mfma_f32_32x32x16_bf16(WA1lo[2], b1h.v, bhnC, 0, 0, 0);
    aNh = __builtin_amdgcn_mfma_f32_32x32x16_bf16(WA2lo[2], b2h.v, aNh, 0, 0, 0);
    aNh = __builtin_amdgcn_mfma_f32_32x32x16_bf16(WA1hi[2], b1l.v, aNh, 0, 0, 0);
    aNh = __builtin_amdgcn_mfma_f32_32x32x16_bf16(WA2hi[2], b2l.v, aNh, 0, 0, 0);
    aNh = __builtin_amdgcn_mfma_f32_32x32x16_bf16(WA1hi[2], b1h.v, aNh, 0, 0, 0);
    aNh = __builtin_amdgcn_mfma_f32_32x32x16_bf16(WA2hi[2], b2h.v, aNh, 0, 0, 0);

#pragma unroll
    for (int i = 0; i < 16; ++i) {
      float r = sigm(aR[i]);
      float z = sigm(aZ[i]);
      float n = tanh_fast(aNi[i] + r * aNh[i]);
      hst[i] = n + z * (hst[i] - n);
    }
  }

#pragma unroll
  for (int k = 0; k < 8; ++k) {
    int u = ((2 * k) & 3) + 8 * ((2 * k) >> 2) + 4 * s;
    *(float2*)(&Hfin[c * 36 + u]) = make_float2(hst[2 * k], hst[2 * k + 1]);
  }
  __syncthreads();
  {
    int mm = lane >> 1, half = lane & 1;
    int onode = blockIdx.x * 32 + mm;
    if (onode < N_NODES) {
      const float* src = &Hfin[mm * 36 + half * 16];
      float4 v0 = *(const float4*)(src);
      float4 v1 = *(const float4*)(src + 4);
      float4 v2 = *(const float4*)(src + 8);
      float4 v3 = *(const float4*)(src + 12);
      float* dst = Y + onode * CH + half * 16;
      *(float4*)(dst) = v0; *(float4*)(dst + 4) = v1;
      *(float4*)(dst + 8) = v2; *(float4*)(dst + 12) = v3;
    }
  }
}

// ---------------- node degree counting ----------------
__global__ __launch_bounds__(256) void deg_kernel(
    const int* __restrict__ nodes, int* __restrict__ DN)
{
  int i = blockIdx.x * 256 + threadIdx.x;
  if (i < N_INC) atomicAdd(&DN[nodes[i]], 1);
}

// ---------------- parallel node-degree scan: phase 1 (block sums) ----------------
__global__ __launch_bounds__(256) void nsum_kernel(
    const int* __restrict__ DN, int* __restrict__ Bsum)
{
  int t = threadIdx.x, i = blockIdx.x * 256 + t;
  int v = (i < N_NODES) ? DN[i] : 0;
#pragma unroll
  for (int off = 1; off < 64; off <<= 1) v += __shfl_xor(v, off);
  __shared__ int red[4];
  if ((t & 63) == 0) red[t >> 6] = v;
  __syncthreads();
  if (t == 0) Bsum[blockIdx.x] = red[0] + red[1] + red[2] + red[3];
}

// ---------------- phase 2: scan of NSB block sums (1 block) ----------------
__global__ __launch_bounds__(256) void bscan_kernel(
    const int* __restrict__ Bsum, int* __restrict__ Boff, int* __restrict__ NOFF)
{
  __shared__ int part[256];
  int t = threadIdx.x;
  int x = (t < NSB) ? Bsum[t] : 0;
  part[t] = x;
  __syncthreads();
  for (int d = 1; d < 256; d <<= 1) {
    int v = (t >= d) ? part[t - d] : 0;
    __syncthreads();
    part[t] += v;
    __syncthreads();
  }
  if (t < NSB) Boff[t] = part[t] - x;
  if (t == NSB - 1) NOFF[N_NODES] = part[t];
}

// ---------------- phase 3: per-block local scan + offset -> NOFF, CUR ----------------
__global__ __launch_bounds__(256) void napply_kernel(
    const int* __restrict__ DN, const int* __restrict__ Boff,
    int* __restrict__ NOFF, int* __restrict__ CUR)
{
  __shared__ int part[256];
  int t = threadIdx.x, i = blockIdx.x * 256 + t;
  int x = (i < N_NODES) ? DN[i] : 0;
  part[t] = x;
  __syncthreads();
  for (int d = 1; d < 256; d <<= 1) {
    int v = (t >= d) ? part[t - d] : 0;
    __syncthreads();
    part[t] += v;
    __syncthreads();
  }
  if (i < N_NODES) {
    int excl = part[t] - x + Boff[blockIdx.x];
    NOFF[i] = excl;
    CUR[i] = excl;
  }
}

// ---------------- bucket incidences by node: INCN[pos] = edge ----------------
__global__ __launch_bounds__(256) void bucket_kernel(
    const int* __restrict__ nodes, const int* __restrict__ edges,
    int* __restrict__ CUR, int* __restrict__ INCN)
{
  int i = blockIdx.x * 256 + threadIdx.x;
  if (i < N_INC) {
    int p = atomicAdd(&CUR[nodes[i]], 1);
    INCN[p] = edges[i];
  }
}

// ---------------- node->edge gather-sum + fused theta (range via binary search) ----------------
__global__ __launch_bounds__(256) void edge_gather_kernel(
    const float* __restrict__ X, const int* __restrict__ nodes,
    const int* __restrict__ edges, const float* __restrict__ theta,
    float* __restrict__ EF)
{
  int e = blockIdx.x;
  int lo = 0, hi = N_INC;
  while (lo < hi) { int mid = (lo + hi) >> 1; if (edges[mid] < e) lo = mid + 1; else hi = mid; }
  int s = lo;
  hi = N_INC;
  while (lo < hi) { int mid = (lo + hi) >> 1; if (edges[mid] < e + 1) lo = mid + 1; else hi = mid; }
  int tE = lo;

  int f = threadIdx.x & 31, g = threadIdx.x >> 5;
  float a0 = 0.f, a1 = 0.f;
  for (int i = s + g; i < tE; i += 16) {
    a0 += X[nodes[i] * CH + f];
    if (i + 8 < tE) a1 += X[nodes[i + 8] * CH + f];
  }
  __shared__ float red[8][33];
  __shared__ __align__(16) float e32[32];
  red[g][f] = a0 + a1;
  __syncthreads();
  if (threadIdx.x < 32) {
    float acc = 0.f;
#pragma unroll
    for (int r = 0; r < 8; ++r) acc += red[r][f];
    int cnt = tE - s;
    float binv = cnt > 0 ? 1.f / (float)cnt : 0.f;
    e32[f] = acc * binv;
    float s0 = 0.f, s1 = 0.f;
#pragma unroll
    for (int k4 = 0; k4 < 8; ++k4) {
      float4 ev = *(float4*)(e32 + 4 * k4);
      float4 tv = *(const float4*)(theta + f * CH + 4 * k4);
      s0 += tv.x * ev.x + tv.z * ev.z;
      s1 += tv.y * ev.y + tv.w * ev.w;
    }
    EF[e * CH + f] = s0 + s1;
  }
}

// ---------------- edge->node CSR gather + finalize (conv1) ----------------
__global__ __launch_bounds__(256) void node_gather_kernel(
    const float* __restrict__ EF, const int* __restrict__ NOFF,
    const int* __restrict__ INCN, const float* __restrict__ bias,
    float* __restrict__ X)
{
  int gid = blockIdx.x * 256 + threadIdx.x;
  if (gid >= N_NODES * 8) return;
  int n = gid >> 3, q = gid & 7;
  int s = NOFF[n], e = NOFF[n + 1];
  float4 acc = make_float4(0.f, 0.f, 0.f, 0.f);
  float4 acc2 = make_float4(0.f, 0.f, 0.f, 0.f);
  int k = s;
  for (; k + 1 < e; k += 2) {
    int e0 = INCN[k], e1 = INCN[k + 1];
    float4 v0 = *(const float4*)(EF + e0 * CH + q * 4);
    float4 v1 = *(const float4*)(EF + e1 * CH + q * 4);
    acc.x += v0.x; acc.y += v0.y; acc.z += v0.z; acc.w += v0.w;
    acc2.x += v1.x; acc2.y += v1.y; acc2.z += v1.z; acc2.w += v1.w;
  }
  if (k < e) {
    float4 v0 = *(const float4*)(EF + INCN[k] * CH + q * 4);
    acc.x += v0.x; acc.y += v0.y; acc.z += v0.z; acc.w += v0.w;
  }
  int d = e - s;
  float dinv = d > 0 ? 1.f / (float)d : 0.f;
  float4 b = *(const float4*)(bias + 4 * q);
  float4 o;
  o.x = leaky(fmaf(acc.x + acc2.x, dinv, b.x));
  o.y = leaky(fmaf(acc.y + acc2.y, dinv, b.y));
  o.z = leaky(fmaf(acc.z + acc2.z, dinv, b.z));
  o.w = leaky(fmaf(acc.w + acc2.w, dinv, b.w));
  *(float4*)(X + n * CH + 4 * q) = o;
}

// ---------------- edge->node CSR gather + finalize + output linear (conv2) ----------------
__global__ __launch_bounds__(256) void node_gather_out_kernel(
    const float* __restrict__ EF, const int* __restrict__ NOFF,
    const int* __restrict__ INCN, const float* __restrict__ bias,
    const float* __restrict__ w_out, const float* __restrict__ b_out,
    float* __restrict__ out)
{
  int gid = blockIdx.x * 256 + threadIdx.x;
  if (gid >= N_NODES * 8) return;
  int n = gid >> 3, q = gid & 7;
  int s = NOFF[n], e = NOFF[n + 1];
  float4 acc = make_float4(0.f, 0.f, 0.f, 0.f);
  float4 acc2 = make_float4(0.f, 0.f, 0.f, 0.f);
  int k = s;
  for (; k + 1 < e; k += 2) {
    int e0 = INCN[k], e1 = INCN[k + 1];
    float4 v0 = *(const float4*)(EF + e0 * CH + q * 4);
    float4 v1 = *(const float4*)(EF + e1 * CH + q * 4);
    acc.x += v0.x; acc.y += v0.y; acc.z += v0.z; acc.w += v0.w;
    acc2.x += v1.x; acc2.y += v1.y; acc2.z += v1.z; acc2.w += v1.w;
  }
  if (k < e) {
    float4 v0 = *(const float4*)(EF + INCN[k] * CH + q * 4);
    acc.x += v0.x; acc.y += v0.y; acc.z += v0.z; acc.w += v0.w;
  }
  int d = e - s;
  float dinv = d > 0 ? 1.f / (float)d : 0.f;
  float4 b = *(const float4*)(bias + 4 * q);
  float v0 = leaky(fmaf(acc.x + acc2.x, dinv, b.x));
  float v1 = leaky(fmaf(acc.y + acc2.y, dinv, b.y));
  float v2 = leaky(fmaf(acc.z + acc2.z, dinv, b.z));
  float v3 = leaky(fmaf(acc.w + acc2.w, dinv, b.w));

  float p[OUTF];
#pragma unroll
  for (int o = 0; o < OUTF; ++o) {
    const float* wr = w_out + o * CH + 4 * q;
    p[o] = v0 * wr[0] + v1 * wr[1] + v2 * wr[2] + v3 * wr[3];
  }
#pragma unroll
  for (int off = 1; off < 8; off <<= 1) {
#pragma unroll
    for (int o = 0; o < OUTF; ++o) p[o] += __shfl_xor(p[o], off);
  }
  if (q < OUTF) out[n * OUTF + q] = leaky(p[q] + b_out[q]);
}

extern "C" void kernel_launch(void* const* d_in, const int* in_sizes, int n_in,
                              void* d_out, int out_size, void* d_ws, size_t ws_size,
                              hipStream_t stream)
{
  const float* price   = (const float*)d_in[0];
  const int*   e_nodes = (const int*)d_in[1];
  const int*   e_edges = (const int*)d_in[2];
  const float* w_ih    = (const float*)d_in[6];
  const float* w_hh    = (const float*)d_in[7];
  const float* b_ih    = (const float*)d_in[8];
  const float* b_hh    = (const float*)d_in[9];
  const float* theta1  = (const float*)d_in[10];
  const float* bias1   = (const float*)d_in[11];
  const float* theta2  = (const float*)d_in[12];
  const float* bias2   = (const float*)d_in[13];
  const float* w_out   = (const float*)d_in[14];
  const float* b_out   = (const float*)d_in[15];
  float* out = (float*)d_out;

  float* ws   = (float*)d_ws;
  float* Y    = ws;                    // [50000*32]
  float* EF   = ws + 1600000;          // [2000*32]
  int*   DN   = (int*)(ws + 1664000);  // [50000]
  int*   NOFF = DN + N_NODES;          // [50001]
  int*   CUR  = NOFF + N_NODES + 1;    // [50000]
  int*   INCN = CUR + N_NODES;         // [200000]
  int*   Bsum = INCN + N_INC;          // [NSB]
  int*   Boff = Bsum + NSB;            // [NSB]

  hipMemsetAsync(DN, 0, N_NODES * sizeof(int), stream);
  deg_kernel<<<(N_INC + 255) / 256, 256, 0, stream>>>(e_nodes, DN);
  nsum_kernel<<<NSB, 256, 0, stream>>>(DN, Bsum);
  bscan_kernel<<<1, 256, 0, stream>>>(Bsum, Boff, NOFF);
  napply_kernel<<<NSB, 256, 0, stream>>>(DN, Boff, NOFF, CUR);
  bucket_kernel<<<(N_INC + 255) / 256, 256, 0, stream>>>(e_nodes, e_edges, CUR, INCN);

  gru_mfma_kernel<<<(N_NODES + 31) / 32, 64, 0, stream>>>(
      price, w_ih, w_hh, b_ih, b_hh, Y);

  edge_gather_kernel<<<N_EDGESC, 256, 0, stream>>>(Y, e_nodes, e_edges, theta1, EF);
  node_gather_kernel<<<(N_NODES * 8 + 255) / 256, 256, 0, stream>>>(EF, NOFF, INCN, bias1, Y);

  edge_gather_kernel<<<N_EDGESC, 256, 0, stream>>>(Y, e_nodes, e_edges, theta2, EF);
  node_gather_out_kernel<<<(N_NODES * 8 + 255) / 256, 256, 0, stream>>>(
      EF, NOFF, INCN, bias2, w_out, b_out, out);
}